// Round 15
// baseline (81.598 us; speedup 1.0000x reference)
//
#include <hip/hip_runtime.h>
#include <hip/hip_bf16.h>

typedef __attribute__((ext_vector_type(4))) float f32x4;
typedef __attribute__((ext_vector_type(8))) short short8;

#define P_TOT 16384
#define NCO 128
#define EPS 1e-5f
// log2(e) / sqrt(128)
#define ALPHA 0.12752269f

__device__ __forceinline__ unsigned short f2bf(float f) {
  union { float f; unsigned u; } v; v.f = f;
  unsigned r = v.u + 0x7FFFu + ((v.u >> 16) & 1u);
  return (unsigned short)(r >> 16);
}
__device__ __forceinline__ float bf2f(unsigned short h) {
  union { unsigned u; float f; } v; v.u = ((unsigned)h) << 16;
  return v.f;
}
__device__ __forceinline__ unsigned cvtpk_bf16(float lo, float hi) {
  unsigned r;
  asm("v_cvt_pk_bf16_f32 %0, %1, %2" : "=v"(r) : "v"(lo), "v"(hi));
  return r;
}
__device__ __forceinline__ void gload16(const void* g, void* l) {
  __builtin_amdgcn_global_load_lds(
      (const __attribute__((address_space(1))) unsigned*)g,
      (__attribute__((address_space(3))) unsigned*)l, 16, 0, 0);
}

// ---------------------------------------------------------------------------
// MFMA 1x1 conv + BN(eval) + ReLU for BOTH modalities (zz&1 = batch,
// zz>>1 = modality). Block = 128p x 128co, BK = 64.
// (byte-identical to rounds 4-14 — verified passing)
// ---------------------------------------------------------------------------
__global__ __launch_bounds__(256) void proj_mfma(
    const float* __restrict__ Xl, const float* __restrict__ Xi,
    const float* __restrict__ Wl, const float* __restrict__ Wi,
    const float* __restrict__ lgm, const float* __restrict__ lbt,
    const float* __restrict__ lmn, const float* __restrict__ lvr,
    const float* __restrict__ igm, const float* __restrict__ ibt,
    const float* __restrict__ imn, const float* __restrict__ ivr,
    unsigned short* __restrict__ Lp, unsigned short* __restrict__ Ip,
    unsigned short* __restrict__ Vg)
{
  __shared__ __align__(16) char smem[36352];
  float* sc_l = (float*)(smem + 35328);
  float* sh_l = (float*)(smem + 35840);

  const int t = threadIdx.x;
  const int w = t >> 6, l = t & 63, l15 = l & 15, g = l >> 4;
  const int zz = blockIdx.y, b = zz & 1, mod = zz >> 1;
  const int pb = blockIdx.x * 128;

  const float* Xg = mod ? Xi : Xl;
  const float* Wg = mod ? Wi : Wl;
  const int Cin = mod ? 512 : 256;
  unsigned short* outp = mod ? Ip : Lp;

  if (t < 128) {
    const float* G = mod ? igm : lgm;
    const float* Bt = mod ? ibt : lbt;
    const float* M = mod ? imn : lmn;
    const float* V = mod ? ivr : lvr;
    float s = G[t] / sqrtf(V[t] + EPS);
    sc_l[t] = s;
    sh_l[t] = Bt[t] - M[t] * s;
  }

  f32x4 o[2][8];
#pragma unroll
  for (int qt = 0; qt < 2; ++qt)
#pragma unroll
    for (int nt = 0; nt < 8; ++nt) o[qt][nt] = (f32x4){0.f, 0.f, 0.f, 0.f};

  uint2 xr[8], wr[8];
  auto load_tiles = [&](int s) {
    int cc = s * 64;
#pragma unroll
    for (int i = 0; i < 8; ++i) {
      int e = t + 256 * i;
      int c = e >> 5, p4 = e & 31;
      f32x4 x = *(const f32x4*)(Xg + ((size_t)(b * Cin + cc + c)) * P_TOT + pb + p4 * 4);
      xr[i].x = cvtpk_bf16(x[0], x[1]);
      xr[i].y = cvtpk_bf16(x[2], x[3]);
    }
#pragma unroll
    for (int i = 0; i < 8; ++i) {
      int e = t + 256 * i;
      int co = e >> 4, c4 = e & 15;
      f32x4 wv = *(const f32x4*)(Wg + (size_t)co * Cin + cc + c4 * 4);
      wr[i].x = cvtpk_bf16(wv[0], wv[1]);
      wr[i].y = cvtpk_bf16(wv[2], wv[3]);
    }
  };

  load_tiles(0);
  const int nsteps = Cin >> 6;
  for (int s = 0; s < nsteps; ++s) {
    __syncthreads();
#pragma unroll
    for (int i = 0; i < 8; ++i) {
      int e = t + 256 * i;
      int c = e >> 5, p4 = e & 31;
      *(uint2*)(smem + c * 264 + p4 * 8) = xr[i];
    }
#pragma unroll
    for (int i = 0; i < 8; ++i) {
      int e = t + 256 * i;
      int co = e >> 4, c4 = e & 15;
      *(uint2*)(smem + 16896 + co * 144 + c4 * 8) = wr[i];
    }
    if (s + 1 < nsteps) load_tiles(s + 1);
    __syncthreads();

#pragma unroll
    for (int kkc = 0; kkc < 2; ++kkc) {
      short8 a[2];
#pragma unroll
      for (int qt = 0; qt < 2; ++qt) {
        const char* ab = smem + (kkc * 32 + g * 8) * 264 + (w * 32 + qt * 16 + l15) * 2;
        union { unsigned uu[4]; short8 v; } cv;
#pragma unroll
        for (int e2 = 0; e2 < 4; ++e2) {
          unsigned lo = *(const unsigned short*)(ab + (2 * e2) * 264);
          unsigned hi = *(const unsigned short*)(ab + (2 * e2 + 1) * 264);
          cv.uu[e2] = lo | (hi << 16);
        }
        a[qt] = cv.v;
      }
#pragma unroll
      for (int nt = 0; nt < 8; ++nt) {
        short8 wf = *(const short8*)(smem + 16896 + (nt * 16 + l15) * 144 + kkc * 64 + g * 16);
        o[0][nt] = __builtin_amdgcn_mfma_f32_16x16x32_bf16(a[0], wf, o[0][nt], 0, 0, 0);
        o[1][nt] = __builtin_amdgcn_mfma_f32_16x16x32_bf16(a[1], wf, o[1][nt], 0, 0, 0);
      }
    }
  }

  __syncthreads();
#pragma unroll
  for (int nt = 0; nt < 8; ++nt) {
    float scv = sc_l[nt * 16 + l15];
    float shv = sh_l[nt * 16 + l15];
#pragma unroll
    for (int qt = 0; qt < 2; ++qt)
#pragma unroll
      for (int r = 0; r < 4; ++r) {
        int p = w * 32 + qt * 16 + 4 * g + r;
        float y = fmaxf(fmaf(o[qt][nt][r], scv, shv), 0.f);
        *(unsigned short*)(smem + p * 272 + (nt * 16 + l15) * 2) = f2bf(y);
      }
  }
  __syncthreads();
  {
    int p = t >> 1, half = t & 1;
    const char* Tb = smem + p * 272 + half * 128;
    unsigned short* ob = outp + ((size_t)b * P_TOT + pb + p) * NCO + half * 64;
#pragma unroll
    for (int i = 0; i < 8; ++i)
      *(uint4*)(ob + i * 8) = *(const uint4*)(Tb + i * 16);
  }
  if (mod == 0) {
    int co = t & 127, ph = t >> 7;
    unsigned short* vb = Vg + ((size_t)b * NCO + co) * P_TOT + pb + ph * 64;
    unsigned pkv[32];
#pragma unroll
    for (int j2 = 0; j2 < 32; ++j2) {
      unsigned lo = *(const unsigned short*)(smem + (ph * 64 + 2 * j2) * 272 + co * 2);
      unsigned hi = *(const unsigned short*)(smem + (ph * 64 + 2 * j2 + 1) * 272 + co * 2);
      pkv[j2] = lo | (hi << 16);
    }
#pragma unroll
    for (int i = 0; i < 8; ++i)
      *(uint4*)(vb + i * 8) = *(const uint4*)&pkv[i * 4];
  }
}

// ---------------------------------------------------------------------------
// Block-diagonal flash attention + blend. Round-15 = round-12 structure with
// the 64-k tile processed as its two natural 32-k halves (nt{0,1}<->kk2=0,
// nt{2,3}<->kk2=1), each a standard online-softmax step. Both halves' QK^T
// MFMAs are issued up front, so softmax0 (VALU) overlaps QK^T(half1) and
// softmax1 overlaps PV(half0) — removes the all-nt max-tree join point.
// Same register footprint; staging/barriers/combine byte-identical to r12.
// ---------------------------------------------------------------------------
__global__ __launch_bounds__(512) void attn_kernel(
    const unsigned short* __restrict__ Lp,  // [B][P][128] bf16 (K rows)
    const unsigned short* __restrict__ Ip,  // [B][P][128] bf16 (Q rows)
    const unsigned short* __restrict__ Vg,  // [B][128][P] bf16 (V cols)
    const float* __restrict__ mw,           // [2]
    float* __restrict__ out)                // [B][128][P] f32
{
  // main: [hb, hb+32768) K dbuf, [hb+32768, hb+65536) V dbuf (hb = half*65536)
  // merge: Tp f32 [128][132] @ 0, m1a @ 67584, l1a @ 68096
  __shared__ __align__(16) char smem[131072];

  const int t = threadIdx.x;
  const int half = t >> 8;       // k-half this wave-group owns
  const int t2 = t & 255;
  const int w = t2 >> 6, l = t & 63;
  const int l15 = l & 15, g = l >> 4;
  const int hb = half << 16;
  // XCD swizzle: gid%8 == chunk
  const int gid = blockIdx.x;
  const int bx = gid >> 4;
  const int chunk = gid & 7;
  const int b = (gid >> 3) & 1;
  const int pq0 = chunk * 2048 + bx * 128;
  const int qw = pq0 + w * 32;

  short8 qf[2][4];
#pragma unroll
  for (int qt = 0; qt < 2; ++qt)
#pragma unroll
    for (int kkc = 0; kkc < 4; ++kkc)
      qf[qt][kkc] = *(const short8*)(Ip +
          ((size_t)b * P_TOT + qw + qt * 16 + l15) * NCO + kkc * 32 + g * 8);

  const char* srcK[4];
  const char* srcV[4];
  int ldsOff[4];
#pragma unroll
  for (int i = 0; i < 4; ++i) {
    int pos = (w * 4 + i) * 4 + (l >> 4);
    int nt = pos >> 4, gp = (pos >> 2) & 3, rr = pos & 3;
    int kp = (nt >> 1) * 32 + gp * 8 + (nt & 1) * 4 + rr;
    srcK[i] = (const char*)Lp +
              ((size_t)b * P_TOT + chunk * 2048 + half * 1024 + kp) * 256 +
              (((l & 15) * 16) ^ ((pos & 7) << 4));
    int c = (w * 4 + i) * 8 + (l >> 3);
    srcV[i] = (const char*)Vg +
              (((size_t)(b * NCO + c)) * P_TOT + chunk * 2048 + half * 1024) * 2 +
              (((l & 7) * 16) ^ ((c & 7) << 4));
    ldsOff[i] = hb + (w * 4 + i) * 1024;
  }

  float m_[2] = {-1e30f, -1e30f}, lsum[2] = {0.f, 0.f};
  f32x4 o[2][8];
#pragma unroll
  for (int qt = 0; qt < 2; ++qt)
#pragma unroll
    for (int ct = 0; ct < 8; ++ct) o[qt][ct] = (f32x4){0.f, 0.f, 0.f, 0.f};

  // one 32-k online-softmax step: softmax on s (2 nt), then PV kk2 quadrant
  auto process_half = [&](f32x4 (&s)[2][2], const char* Vb, int kk2) {
    unsigned pk[2][4];
    float f_[2];
    int upd[2];
#pragma unroll
    for (int qt = 0; qt < 2; ++qt) {
      float v0 = fmaxf(fmaxf(s[qt][0][0], s[qt][0][1]), fmaxf(s[qt][0][2], s[qt][0][3]));
      float v1 = fmaxf(fmaxf(s[qt][1][0], s[qt][1][1]), fmaxf(s[qt][1][2], s[qt][1][3]));
      float v = fmaxf(v0, v1);
      // conditional defer-max (verified r12): decision on per-lane partials;
      // full cross-lane reduce only when updating
      upd[qt] = __any(v * ALPHA > m_[qt] + 8.f);
      float mn = m_[qt];
      if (upd[qt]) {
        float vv = fmaxf(v, __shfl_xor(v, 16));
        vv = fmaxf(vv, __shfl_xor(vv, 32));
        mn = fmaxf(m_[qt], vv * ALPHA);
        f_[qt] = __builtin_amdgcn_exp2f(m_[qt] - mn);
        m_[qt] = mn;
      } else {
        f_[qt] = 1.f;
      }
      float ps = 0.f;
#pragma unroll
      for (int nt = 0; nt < 2; ++nt)
#pragma unroll
        for (int r = 0; r < 4; ++r) {
          float p = __builtin_amdgcn_exp2f(s[qt][nt][r] * ALPHA - mn);
          s[qt][nt][r] = p;
          ps += p;
        }
      pk[qt][0] = cvtpk_bf16(s[qt][0][0], s[qt][0][1]);
      pk[qt][1] = cvtpk_bf16(s[qt][0][2], s[qt][0][3]);
      pk[qt][2] = cvtpk_bf16(s[qt][1][0], s[qt][1][1]);
      pk[qt][3] = cvtpk_bf16(s[qt][1][2], s[qt][1][3]);
      ps += __shfl_xor(ps, 16);
      ps += __shfl_xor(ps, 32);
      lsum[qt] = lsum[qt] * f_[qt] + ps;
    }
#pragma unroll
    for (int qt = 0; qt < 2; ++qt)
      if (upd[qt]) {
#pragma unroll
        for (int r = 0; r < 4; ++r) {
          float fb = __shfl(f_[qt], 20 * g + r);
#pragma unroll
          for (int ct = 0; ct < 8; ++ct) o[qt][ct][r] *= fb;
        }
      }
    short8 af[2];
#pragma unroll
    for (int qt = 0; qt < 2; ++qt) {
      union { unsigned u[4]; short8 v; } x;
      x.u[0] = pk[qt][0];
      x.u[1] = pk[qt][1];
      x.u[2] = pk[qt][2];
      x.u[3] = pk[qt][3];
      af[qt] = x.v;
    }
#pragma unroll
    for (int ct = 0; ct < 8; ++ct) {
      short8 vf = *(const short8*)(Vb + (ct * 16 + l15) * 128 +
                      ((kk2 * 64 + g * 16) ^ ((l15 & 7) << 4)));
      o[0][ct] = __builtin_amdgcn_mfma_f32_16x16x32_bf16(af[0], vf, o[0][ct], 0, 0, 0);
      o[1][ct] = __builtin_amdgcn_mfma_f32_16x16x32_bf16(af[1], vf, o[1][ct], 0, 0, 0);
    }
  };

#pragma unroll
  for (int i = 0; i < 4; ++i) {
    gload16(srcK[i], smem + ldsOff[i]);
    gload16(srcV[i], smem + 32768 + ldsOff[i]);
  }
  __syncthreads();

  int cur = 0;
  for (int kt = 0; kt < 16; ++kt) {
    if (kt + 1 < 16) {
#pragma unroll
      for (int i = 0; i < 4; ++i) {
        gload16(srcK[i] + (size_t)(kt + 1) * 16384,
                smem + (cur ^ 1) * 16384 + ldsOff[i]);
        gload16(srcV[i] + (size_t)(kt + 1) * 128,
                smem + 32768 + (cur ^ 1) * 16384 + ldsOff[i]);
      }
    }
    const char* Kb = smem + hb + cur * 16384;
    const char* Vb = smem + hb + 32768 + cur * 16384;

    f32x4 s0[2][2], s1[2][2];
#pragma unroll
    for (int qt = 0; qt < 2; ++qt)
#pragma unroll
      for (int nt = 0; nt < 2; ++nt) {
        s0[qt][nt] = (f32x4){0.f, 0.f, 0.f, 0.f};
        s1[qt][nt] = (f32x4){0.f, 0.f, 0.f, 0.f};
      }
    // QK^T half 0 (pi rows 0..31)
#pragma unroll
    for (int kkc = 0; kkc < 4; ++kkc) {
#pragma unroll
      for (int nt = 0; nt < 2; ++nt) {
        short8 kf = *(const short8*)(Kb + (nt * 16 + l15) * 256 +
                        ((kkc * 64 + g * 16) ^ ((l15 & 7) << 4)));
        s0[0][nt] = __builtin_amdgcn_mfma_f32_16x16x32_bf16(kf, qf[0][kkc], s0[0][nt], 0, 0, 0);
        s0[1][nt] = __builtin_amdgcn_mfma_f32_16x16x32_bf16(kf, qf[1][kkc], s0[1][nt], 0, 0, 0);
      }
    }
    // QK^T half 1 (pi rows 32..63) — issued before softmax0 so the MFMA
    // pipe stays busy while the VALU runs softmax0
#pragma unroll
    for (int kkc = 0; kkc < 4; ++kkc) {
#pragma unroll
      for (int nt = 0; nt < 2; ++nt) {
        short8 kf = *(const short8*)(Kb + ((nt + 2) * 16 + l15) * 256 +
                        ((kkc * 64 + g * 16) ^ ((l15 & 7) << 4)));
        s1[0][nt] = __builtin_amdgcn_mfma_f32_16x16x32_bf16(kf, qf[0][kkc], s1[0][nt], 0, 0, 0);
        s1[1][nt] = __builtin_amdgcn_mfma_f32_16x16x32_bf16(kf, qf[1][kkc], s1[1][nt], 0, 0, 0);
      }
    }

    process_half(s0, Vb, 0);   // softmax0 overlaps QK^T(half1) in flight
    process_half(s1, Vb, 1);   // softmax1 overlaps PV(half0) in flight

    __syncthreads();
    cur ^= 1;
  }

  // ---- flash combine across the two k-halves (round-6/12 verified code)
  float* Tp = (float*)smem;               // [128][132] f32
  float* m1a = (float*)(smem + 67584);    // [128]
  float* l1a = (float*)(smem + 68096);    // [128]

  if (half == 1) {
#pragma unroll
    for (int qt = 0; qt < 2; ++qt) {
      int qb = w * 32 + qt * 16 + 4 * g;
#pragma unroll
      for (int ct = 0; ct < 8; ++ct) {
        int c = ct * 16 + l15;
        *(f32x4*)&Tp[c * 132 + qb] = o[qt][ct];
      }
      if (g == 0) {
        m1a[w * 32 + qt * 16 + l15] = m_[qt];
        l1a[w * 32 + qt * 16 + l15] = lsum[qt];
      }
    }
  }
  __syncthreads();

  float a0 = mw[0], a1 = mw[1];
  float mx = fmaxf(a0, a1);
  float e0 = __builtin_amdgcn_exp2f((a0 - mx) * 1.442695041f);
  float e1 = __builtin_amdgcn_exp2f((a1 - mx) * 1.442695041f);
  float w0m = e0 / (e0 + e1), w1m = e1 / (e0 + e1);

  if (half == 0) {
#pragma unroll
    for (int qt = 0; qt < 2; ++qt) {
      int qb = w * 32 + qt * 16 + 4 * g;
      f32x4 m1v = *(const f32x4*)&m1a[qb];
      f32x4 l1v = *(const f32x4*)&l1a[qb];
      float A[4], Bc[4];
#pragma unroll
      for (int r = 0; r < 4; ++r) {
        float m0r = __shfl(m_[qt], 20 * g + r);
        float l0r = __shfl(lsum[qt], 20 * g + r);
        float M = fmaxf(m0r, m1v[r]);
        float w0h = __builtin_amdgcn_exp2f(m0r - M);
        float w1h = __builtin_amdgcn_exp2f(m1v[r] - M);
        float L = w0h * l0r + w1h * l1v[r];
        A[r] = w1m * w0h / L;
        Bc[r] = w1m * w1h / L;
      }
#pragma unroll
      for (int ct = 0; ct < 8; ++ct) {
        int c = ct * 16 + l15;
        f32x4 o1 = *(const f32x4*)&Tp[c * 132 + qb];
#pragma unroll
        for (int r = 0; r < 4; ++r)
          o[qt][ct][r] = A[r] * o[qt][ct][r] + Bc[r] * o1[r];
      }
    }
  }
  __syncthreads();

  if (half == 0) {
#pragma unroll
    for (int qt = 0; qt < 2; ++qt) {
      int qb = w * 32 + qt * 16 + 4 * g;
#pragma unroll
      for (int ct = 0; ct < 8; ++ct) {
        int c = ct * 16 + l15;
        f32x4 v = o[qt][ct];
#pragma unroll
        for (int r = 0; r < 4; ++r) {
          float img = bf2f(Ip[((size_t)b * P_TOT + pq0 + qb + r) * NCO + c]);
          v[r] = w0m * img + v[r];
        }
        *(f32x4*)&Tp[c * 132 + qb] = v;
      }
    }
  }
  __syncthreads();
  {
    int cc = t >> 5;            // 0..15
    int q0 = (t & 31) * 4;      // 0..124
#pragma unroll
    for (int i2 = 0; i2 < 8; ++i2) {
      int c = cc + i2 * 16;
      float* Ob = out + ((size_t)b * NCO + c) * P_TOT + pq0 + q0;
      *(f32x4*)Ob = *(const f32x4*)&Tp[c * 132 + q0];
    }
  }
}

extern "C" void kernel_launch(void* const* d_in, const int* in_sizes, int n_in,
                              void* d_out, int out_size, void* d_ws, size_t ws_size,
                              hipStream_t stream) {
  const float* lidar = (const float*)d_in[0];
  const float* image = (const float*)d_in[1];
  const float* lw = (const float*)d_in[2];
  const float* lg = (const float*)d_in[3];
  const float* lb = (const float*)d_in[4];
  const float* lm = (const float*)d_in[5];
  const float* lv = (const float*)d_in[6];
  const float* iw = (const float*)d_in[7];
  const float* ig = (const float*)d_in[8];
  const float* ibt = (const float*)d_in[9];
  const float* im = (const float*)d_in[10];
  const float* iv = (const float*)d_in[11];
  const float* mw = (const float*)d_in[12];

  unsigned short* Lp = (unsigned short*)d_ws;            // [2][16384][128] bf16
  unsigned short* Ip = Lp + (size_t)2 * P_TOT * NCO;     // [2][16384][128] bf16
  unsigned short* Vg = Ip + (size_t)2 * P_TOT * NCO;     // [2][128][16384] bf16

  dim3 gp(P_TOT / 128, 4);
  proj_mfma<<<gp, 256, 0, stream>>>(lidar, image, lw, iw,
                                    lg, lb, lm, lv, ig, ibt, im, iv,
                                    Lp, Ip, Vg);

  attn_kernel<<<dim3(256), 512, 0, stream>>>(Lp, Ip, Vg, mw, (float*)d_out);
}

// Round 16
// 79.982 us; speedup vs baseline: 1.0202x; 1.0202x over previous
//
#include <hip/hip_runtime.h>
#include <hip/hip_bf16.h>

typedef __attribute__((ext_vector_type(4))) float f32x4;
typedef __attribute__((ext_vector_type(8))) short short8;

#define P_TOT 16384
#define NCO 128
#define EPS 1e-5f
// log2(e) / sqrt(128)
#define ALPHA 0.12752269f

__device__ __forceinline__ unsigned short f2bf(float f) {
  union { float f; unsigned u; } v; v.f = f;
  unsigned r = v.u + 0x7FFFu + ((v.u >> 16) & 1u);
  return (unsigned short)(r >> 16);
}
__device__ __forceinline__ float bf2f(unsigned short h) {
  union { unsigned u; float f; } v; v.u = ((unsigned)h) << 16;
  return v.f;
}
__device__ __forceinline__ unsigned cvtpk_bf16(float lo, float hi) {
  unsigned r;
  asm("v_cvt_pk_bf16_f32 %0, %1, %2" : "=v"(r) : "v"(lo), "v"(hi));
  return r;
}
__device__ __forceinline__ void gload16(const void* g, void* l) {
  __builtin_amdgcn_global_load_lds(
      (const __attribute__((address_space(1))) unsigned*)g,
      (__attribute__((address_space(3))) unsigned*)l, 16, 0, 0);
}

// ---------------------------------------------------------------------------
// MFMA 1x1 conv + BN(eval) + ReLU for BOTH modalities (zz&1 = batch,
// zz>>1 = modality). Block = 128p x 128co, BK = 64.
// (byte-identical to rounds 4-14 — verified passing)
// ---------------------------------------------------------------------------
__global__ __launch_bounds__(256) void proj_mfma(
    const float* __restrict__ Xl, const float* __restrict__ Xi,
    const float* __restrict__ Wl, const float* __restrict__ Wi,
    const float* __restrict__ lgm, const float* __restrict__ lbt,
    const float* __restrict__ lmn, const float* __restrict__ lvr,
    const float* __restrict__ igm, const float* __restrict__ ibt,
    const float* __restrict__ imn, const float* __restrict__ ivr,
    unsigned short* __restrict__ Lp, unsigned short* __restrict__ Ip,
    unsigned short* __restrict__ Vg)
{
  __shared__ __align__(16) char smem[36352];
  float* sc_l = (float*)(smem + 35328);
  float* sh_l = (float*)(smem + 35840);

  const int t = threadIdx.x;
  const int w = t >> 6, l = t & 63, l15 = l & 15, g = l >> 4;
  const int zz = blockIdx.y, b = zz & 1, mod = zz >> 1;
  const int pb = blockIdx.x * 128;

  const float* Xg = mod ? Xi : Xl;
  const float* Wg = mod ? Wi : Wl;
  const int Cin = mod ? 512 : 256;
  unsigned short* outp = mod ? Ip : Lp;

  if (t < 128) {
    const float* G = mod ? igm : lgm;
    const float* Bt = mod ? ibt : lbt;
    const float* M = mod ? imn : lmn;
    const float* V = mod ? ivr : lvr;
    float s = G[t] / sqrtf(V[t] + EPS);
    sc_l[t] = s;
    sh_l[t] = Bt[t] - M[t] * s;
  }

  f32x4 o[2][8];
#pragma unroll
  for (int qt = 0; qt < 2; ++qt)
#pragma unroll
    for (int nt = 0; nt < 8; ++nt) o[qt][nt] = (f32x4){0.f, 0.f, 0.f, 0.f};

  uint2 xr[8], wr[8];
  auto load_tiles = [&](int s) {
    int cc = s * 64;
#pragma unroll
    for (int i = 0; i < 8; ++i) {
      int e = t + 256 * i;
      int c = e >> 5, p4 = e & 31;
      f32x4 x = *(const f32x4*)(Xg + ((size_t)(b * Cin + cc + c)) * P_TOT + pb + p4 * 4);
      xr[i].x = cvtpk_bf16(x[0], x[1]);
      xr[i].y = cvtpk_bf16(x[2], x[3]);
    }
#pragma unroll
    for (int i = 0; i < 8; ++i) {
      int e = t + 256 * i;
      int co = e >> 4, c4 = e & 15;
      f32x4 wv = *(const f32x4*)(Wg + (size_t)co * Cin + cc + c4 * 4);
      wr[i].x = cvtpk_bf16(wv[0], wv[1]);
      wr[i].y = cvtpk_bf16(wv[2], wv[3]);
    }
  };

  load_tiles(0);
  const int nsteps = Cin >> 6;
  for (int s = 0; s < nsteps; ++s) {
    __syncthreads();
#pragma unroll
    for (int i = 0; i < 8; ++i) {
      int e = t + 256 * i;
      int c = e >> 5, p4 = e & 31;
      *(uint2*)(smem + c * 264 + p4 * 8) = xr[i];
    }
#pragma unroll
    for (int i = 0; i < 8; ++i) {
      int e = t + 256 * i;
      int co = e >> 4, c4 = e & 15;
      *(uint2*)(smem + 16896 + co * 144 + c4 * 8) = wr[i];
    }
    if (s + 1 < nsteps) load_tiles(s + 1);
    __syncthreads();

#pragma unroll
    for (int kkc = 0; kkc < 2; ++kkc) {
      short8 a[2];
#pragma unroll
      for (int qt = 0; qt < 2; ++qt) {
        const char* ab = smem + (kkc * 32 + g * 8) * 264 + (w * 32 + qt * 16 + l15) * 2;
        union { unsigned uu[4]; short8 v; } cv;
#pragma unroll
        for (int e2 = 0; e2 < 4; ++e2) {
          unsigned lo = *(const unsigned short*)(ab + (2 * e2) * 264);
          unsigned hi = *(const unsigned short*)(ab + (2 * e2 + 1) * 264);
          cv.uu[e2] = lo | (hi << 16);
        }
        a[qt] = cv.v;
      }
#pragma unroll
      for (int nt = 0; nt < 8; ++nt) {
        short8 wf = *(const short8*)(smem + 16896 + (nt * 16 + l15) * 144 + kkc * 64 + g * 16);
        o[0][nt] = __builtin_amdgcn_mfma_f32_16x16x32_bf16(a[0], wf, o[0][nt], 0, 0, 0);
        o[1][nt] = __builtin_amdgcn_mfma_f32_16x16x32_bf16(a[1], wf, o[1][nt], 0, 0, 0);
      }
    }
  }

  __syncthreads();
#pragma unroll
  for (int nt = 0; nt < 8; ++nt) {
    float scv = sc_l[nt * 16 + l15];
    float shv = sh_l[nt * 16 + l15];
#pragma unroll
    for (int qt = 0; qt < 2; ++qt)
#pragma unroll
      for (int r = 0; r < 4; ++r) {
        int p = w * 32 + qt * 16 + 4 * g + r;
        float y = fmaxf(fmaf(o[qt][nt][r], scv, shv), 0.f);
        *(unsigned short*)(smem + p * 272 + (nt * 16 + l15) * 2) = f2bf(y);
      }
  }
  __syncthreads();
  {
    int p = t >> 1, half = t & 1;
    const char* Tb = smem + p * 272 + half * 128;
    unsigned short* ob = outp + ((size_t)b * P_TOT + pb + p) * NCO + half * 64;
#pragma unroll
    for (int i = 0; i < 8; ++i)
      *(uint4*)(ob + i * 8) = *(const uint4*)(Tb + i * 16);
  }
  if (mod == 0) {
    int co = t & 127, ph = t >> 7;
    unsigned short* vb = Vg + ((size_t)b * NCO + co) * P_TOT + pb + ph * 64;
    unsigned pkv[32];
#pragma unroll
    for (int j2 = 0; j2 < 32; ++j2) {
      unsigned lo = *(const unsigned short*)(smem + (ph * 64 + 2 * j2) * 272 + co * 2);
      unsigned hi = *(const unsigned short*)(smem + (ph * 64 + 2 * j2 + 1) * 272 + co * 2);
      pkv[j2] = lo | (hi << 16);
    }
#pragma unroll
    for (int i = 0; i < 8; ++i)
      *(uint4*)(vb + i * 8) = *(const uint4*)&pkv[i * 4];
  }
}

// ---------------------------------------------------------------------------
// Block-diagonal flash attention + blend. Final (round-12/14 verified):
// round-6 structure (512 thr = 4 q-waves x 2 k-halves, 64-k tiles, 128 KB
// LDS dbuf, one __syncthreads/iter, XCD swizzle, pi-permuted S^T rows,
// in-lane PV A-frag) + conditional defer-max (cross-lane reduce only on
// rare update).
// ---------------------------------------------------------------------------
__global__ __launch_bounds__(512) void attn_kernel(
    const unsigned short* __restrict__ Lp,  // [B][P][128] bf16 (K rows)
    const unsigned short* __restrict__ Ip,  // [B][P][128] bf16 (Q rows)
    const unsigned short* __restrict__ Vg,  // [B][128][P] bf16 (V cols)
    const float* __restrict__ mw,           // [2]
    float* __restrict__ out)                // [B][128][P] f32
{
  // main: [hb, hb+32768) K dbuf, [hb+32768, hb+65536) V dbuf (hb = half*65536)
  // merge: Tp f32 [128][132] @ 0, m1a @ 67584, l1a @ 68096
  __shared__ __align__(16) char smem[131072];

  const int t = threadIdx.x;
  const int half = t >> 8;       // k-half this wave-group owns
  const int t2 = t & 255;
  const int w = t2 >> 6, l = t & 63;
  const int l15 = l & 15, g = l >> 4;
  const int hb = half << 16;
  // XCD swizzle: gid%8 == chunk
  const int gid = blockIdx.x;
  const int bx = gid >> 4;
  const int chunk = gid & 7;
  const int b = (gid >> 3) & 1;
  const int pq0 = chunk * 2048 + bx * 128;
  const int qw = pq0 + w * 32;

  short8 qf[2][4];
#pragma unroll
  for (int qt = 0; qt < 2; ++qt)
#pragma unroll
    for (int kkc = 0; kkc < 4; ++kkc)
      qf[qt][kkc] = *(const short8*)(Ip +
          ((size_t)b * P_TOT + qw + qt * 16 + l15) * NCO + kkc * 32 + g * 8);

  const char* srcK[4];
  const char* srcV[4];
  int ldsOff[4];
#pragma unroll
  for (int i = 0; i < 4; ++i) {
    int pos = (w * 4 + i) * 4 + (l >> 4);
    int nt = pos >> 4, gp = (pos >> 2) & 3, rr = pos & 3;
    int kp = (nt >> 1) * 32 + gp * 8 + (nt & 1) * 4 + rr;
    srcK[i] = (const char*)Lp +
              ((size_t)b * P_TOT + chunk * 2048 + half * 1024 + kp) * 256 +
              (((l & 15) * 16) ^ ((pos & 7) << 4));
    int c = (w * 4 + i) * 8 + (l >> 3);
    srcV[i] = (const char*)Vg +
              (((size_t)(b * NCO + c)) * P_TOT + chunk * 2048 + half * 1024) * 2 +
              (((l & 7) * 16) ^ ((c & 7) << 4));
    ldsOff[i] = hb + (w * 4 + i) * 1024;
  }

  float m_[2] = {-1e30f, -1e30f}, lsum[2] = {0.f, 0.f};
  f32x4 o[2][8];
#pragma unroll
  for (int qt = 0; qt < 2; ++qt)
#pragma unroll
    for (int ct = 0; ct < 8; ++ct) o[qt][ct] = (f32x4){0.f, 0.f, 0.f, 0.f};

#pragma unroll
  for (int i = 0; i < 4; ++i) {
    gload16(srcK[i], smem + ldsOff[i]);
    gload16(srcV[i], smem + 32768 + ldsOff[i]);
  }
  __syncthreads();

  int cur = 0;
  for (int kt = 0; kt < 16; ++kt) {
    if (kt + 1 < 16) {
#pragma unroll
      for (int i = 0; i < 4; ++i) {
        gload16(srcK[i] + (size_t)(kt + 1) * 16384,
                smem + (cur ^ 1) * 16384 + ldsOff[i]);
        gload16(srcV[i] + (size_t)(kt + 1) * 128,
                smem + 32768 + (cur ^ 1) * 16384 + ldsOff[i]);
      }
    }
    const char* Kb = smem + hb + cur * 16384;
    const char* Vb = smem + hb + 32768 + cur * 16384;

    f32x4 s[2][4];
#pragma unroll
    for (int qt = 0; qt < 2; ++qt)
#pragma unroll
      for (int nt = 0; nt < 4; ++nt) s[qt][nt] = (f32x4){0.f, 0.f, 0.f, 0.f};
#pragma unroll
    for (int kkc = 0; kkc < 4; ++kkc) {
#pragma unroll
      for (int nt = 0; nt < 4; ++nt) {
        short8 kf = *(const short8*)(Kb + (nt * 16 + l15) * 256 +
                        ((kkc * 64 + g * 16) ^ ((l15 & 7) << 4)));
        s[0][nt] = __builtin_amdgcn_mfma_f32_16x16x32_bf16(kf, qf[0][kkc], s[0][nt], 0, 0, 0);
        s[1][nt] = __builtin_amdgcn_mfma_f32_16x16x32_bf16(kf, qf[1][kkc], s[1][nt], 0, 0, 0);
      }
    }

    unsigned pk[2][4][2];
    float f_[2];
    int upd[2];
#pragma unroll
    for (int qt = 0; qt < 2; ++qt) {
      float v0 = fmaxf(fmaxf(s[qt][0][0], s[qt][0][1]), fmaxf(s[qt][0][2], s[qt][0][3]));
      float v1 = fmaxf(fmaxf(s[qt][1][0], s[qt][1][1]), fmaxf(s[qt][1][2], s[qt][1][3]));
      float v2 = fmaxf(fmaxf(s[qt][2][0], s[qt][2][1]), fmaxf(s[qt][2][2], s[qt][2][3]));
      float v3 = fmaxf(fmaxf(s[qt][3][0], s[qt][3][1]), fmaxf(s[qt][3][2], s[qt][3][3]));
      float v = fmaxf(fmaxf(v0, v1), fmaxf(v2, v3));
      // conditional defer-max: decision on per-lane partials (__any covers
      // the row max); full cross-lane reduce only when updating
      upd[qt] = __any(v * ALPHA > m_[qt] + 8.f);
      float mn = m_[qt];
      if (upd[qt]) {
        float vv = fmaxf(v, __shfl_xor(v, 16));
        vv = fmaxf(vv, __shfl_xor(vv, 32));
        mn = fmaxf(m_[qt], vv * ALPHA);
        f_[qt] = __builtin_amdgcn_exp2f(m_[qt] - mn);
        m_[qt] = mn;
      } else {
        f_[qt] = 1.f;
      }
      float ps = 0.f;
#pragma unroll
      for (int nt = 0; nt < 4; ++nt) {
#pragma unroll
        for (int r = 0; r < 4; ++r) {
          float p = __builtin_amdgcn_exp2f(s[qt][nt][r] * ALPHA - mn);
          s[qt][nt][r] = p;
          ps += p;
        }
        pk[qt][nt][0] = cvtpk_bf16(s[qt][nt][0], s[qt][nt][1]);
        pk[qt][nt][1] = cvtpk_bf16(s[qt][nt][2], s[qt][nt][3]);
      }
      ps += __shfl_xor(ps, 16);
      ps += __shfl_xor(ps, 32);
      lsum[qt] = lsum[qt] * f_[qt] + ps;
    }

#pragma unroll
    for (int qt = 0; qt < 2; ++qt)
      if (upd[qt]) {
#pragma unroll
        for (int r = 0; r < 4; ++r) {
          float fb = __shfl(f_[qt], 20 * g + r);
#pragma unroll
          for (int ct = 0; ct < 8; ++ct) o[qt][ct][r] *= fb;
        }
      }

#pragma unroll
    for (int kk2 = 0; kk2 < 2; ++kk2) {
      short8 af[2];
#pragma unroll
      for (int qt = 0; qt < 2; ++qt) {
        union { unsigned u[4]; short8 v; } x;
        x.u[0] = pk[qt][2 * kk2][0];
        x.u[1] = pk[qt][2 * kk2][1];
        x.u[2] = pk[qt][2 * kk2 + 1][0];
        x.u[3] = pk[qt][2 * kk2 + 1][1];
        af[qt] = x.v;
      }
#pragma unroll
      for (int ct = 0; ct < 8; ++ct) {
        short8 vf = *(const short8*)(Vb + (ct * 16 + l15) * 128 +
                        ((kk2 * 64 + g * 16) ^ ((l15 & 7) << 4)));
        o[0][ct] = __builtin_amdgcn_mfma_f32_16x16x32_bf16(af[0], vf, o[0][ct], 0, 0, 0);
        o[1][ct] = __builtin_amdgcn_mfma_f32_16x16x32_bf16(af[1], vf, o[1][ct], 0, 0, 0);
      }
    }
    __syncthreads();
    cur ^= 1;
  }

  // ---- flash combine across the two k-halves (round-6 verified code)
  float* Tp = (float*)smem;               // [128][132] f32
  float* m1a = (float*)(smem + 67584);    // [128]
  float* l1a = (float*)(smem + 68096);    // [128]

  if (half == 1) {
#pragma unroll
    for (int qt = 0; qt < 2; ++qt) {
      int qb = w * 32 + qt * 16 + 4 * g;
#pragma unroll
      for (int ct = 0; ct < 8; ++ct) {
        int c = ct * 16 + l15;
        *(f32x4*)&Tp[c * 132 + qb] = o[qt][ct];
      }
      if (g == 0) {
        m1a[w * 32 + qt * 16 + l15] = m_[qt];
        l1a[w * 32 + qt * 16 + l15] = lsum[qt];
      }
    }
  }
  __syncthreads();

  float a0 = mw[0], a1 = mw[1];
  float mx = fmaxf(a0, a1);
  float e0 = __builtin_amdgcn_exp2f((a0 - mx) * 1.442695041f);
  float e1 = __builtin_amdgcn_exp2f((a1 - mx) * 1.442695041f);
  float w0m = e0 / (e0 + e1), w1m = e1 / (e0 + e1);

  if (half == 0) {
#pragma unroll
    for (int qt = 0; qt < 2; ++qt) {
      int qb = w * 32 + qt * 16 + 4 * g;
      f32x4 m1v = *(const f32x4*)&m1a[qb];
      f32x4 l1v = *(const f32x4*)&l1a[qb];
      float A[4], Bc[4];
#pragma unroll
      for (int r = 0; r < 4; ++r) {
        float m0r = __shfl(m_[qt], 20 * g + r);
        float l0r = __shfl(lsum[qt], 20 * g + r);
        float M = fmaxf(m0r, m1v[r]);
        float w0h = __builtin_amdgcn_exp2f(m0r - M);
        float w1h = __builtin_amdgcn_exp2f(m1v[r] - M);
        float L = w0h * l0r + w1h * l1v[r];
        A[r] = w1m * w0h / L;
        Bc[r] = w1m * w1h / L;
      }
#pragma unroll
      for (int ct = 0; ct < 8; ++ct) {
        int c = ct * 16 + l15;
        f32x4 o1 = *(const f32x4*)&Tp[c * 132 + qb];
#pragma unroll
        for (int r = 0; r < 4; ++r)
          o[qt][ct][r] = A[r] * o[qt][ct][r] + Bc[r] * o1[r];
      }
    }
  }
  __syncthreads();

  if (half == 0) {
#pragma unroll
    for (int qt = 0; qt < 2; ++qt) {
      int qb = w * 32 + qt * 16 + 4 * g;
#pragma unroll
      for (int ct = 0; ct < 8; ++ct) {
        int c = ct * 16 + l15;
        f32x4 v = o[qt][ct];
#pragma unroll
        for (int r = 0; r < 4; ++r) {
          float img = bf2f(Ip[((size_t)b * P_TOT + pq0 + qb + r) * NCO + c]);
          v[r] = w0m * img + v[r];
        }
        *(f32x4*)&Tp[c * 132 + qb] = v;
      }
    }
  }
  __syncthreads();
  {
    int cc = t >> 5;            // 0..15
    int q0 = (t & 31) * 4;      // 0..124
#pragma unroll
    for (int i2 = 0; i2 < 8; ++i2) {
      int c = cc + i2 * 16;
      float* Ob = out + ((size_t)b * NCO + c) * P_TOT + pq0 + q0;
      *(f32x4*)Ob = *(const f32x4*)&Tp[c * 132 + q0];
    }
  }
}

extern "C" void kernel_launch(void* const* d_in, const int* in_sizes, int n_in,
                              void* d_out, int out_size, void* d_ws, size_t ws_size,
                              hipStream_t stream) {
  const float* lidar = (const float*)d_in[0];
  const float* image = (const float*)d_in[1];
  const float* lw = (const float*)d_in[2];
  const float* lg = (const float*)d_in[3];
  const float* lb = (const float*)d_in[4];
  const float* lm = (const float*)d_in[5];
  const float* lv = (const float*)d_in[6];
  const float* iw = (const float*)d_in[7];
  const float* ig = (const float*)d_in[8];
  const float* ibt = (const float*)d_in[9];
  const float* im = (const float*)d_in[10];
  const float* iv = (const float*)d_in[11];
  const float* mw = (const float*)d_in[12];

  unsigned short* Lp = (unsigned short*)d_ws;            // [2][16384][128] bf16
  unsigned short* Ip = Lp + (size_t)2 * P_TOT * NCO;     // [2][16384][128] bf16
  unsigned short* Vg = Ip + (size_t)2 * P_TOT * NCO;     // [2][128][16384] bf16

  dim3 gp(P_TOT / 128, 4);
  proj_mfma<<<gp, 256, 0, stream>>>(lidar, image, lw, iw,
                                    lg, lb, lm, lv, ig, ibt, im, iv,
                                    Lp, Ip, Vg);

  attn_kernel<<<dim3(256), 512, 0, stream>>>(Lp, Ip, Vg, mw, (float*)d_out);
}